// Round 7
// baseline (756.796 us; speedup 1.0000x reference)
//
#include <hip/hip_runtime.h>
#include <hip/hip_bf16.h>
#include <math.h>

#define BD   256    // D
#define NH   8      // heads
#define DH   32     // head dim
#define NB   16     // batch
#define NN   1024   // N
#define LQ   1025   // N+1
#define EPSV 1e-5f

typedef unsigned short ushort_t;
typedef __attribute__((ext_vector_type(8))) short short8;
typedef __attribute__((ext_vector_type(4))) float f32x4;

static __device__ __forceinline__ ushort_t f2b(float x) {
  union { __hip_bfloat16 h; ushort_t u; } cv;
  cv.h = __float2bfloat16(x);
  return cv.u;
}
static __device__ __forceinline__ float b2f(ushort_t u) {
  union { float f; unsigned v; } c; c.v = ((unsigned)u) << 16; return c.f;
}

// ---------------- copy / cast helpers ----------------
__global__ void k_copy_cast(const float* __restrict__ in, float* __restrict__ X,
                            ushort_t* __restrict__ Xh, long n) {
  long stride = (long)gridDim.x * 256;
  for (long i = (long)blockIdx.x * 256 + threadIdx.x; i < n; i += stride) {
    float v = in[i];
    X[i] = v;
    Xh[i] = f2b(v);
  }
}

__global__ void k_sat_out(const float* __restrict__ X, float* __restrict__ out) {
  long n = (long)NB * NN * BD;
  long stride = (long)gridDim.x * 256;
  for (long i = (long)blockIdx.x * 256 + threadIdx.x; i < n; i += stride) {
    long b = i / ((long)NN * BD);
    long r = i - b * ((long)NN * BD);
    out[i] = X[b * (long)LQ * BD + BD + r];
  }
}

// ---------------- weight transpose+cast: Wt[slot][n][k] = bf16(W[k][n]) ----------------
__global__ __launch_bounds__(256) void k_wtrans(const float* __restrict__ Wq,
                                                const float* __restrict__ Wk,
                                                const float* __restrict__ Wv,
                                                const float* __restrict__ Wo,
                                                ushort_t* __restrict__ Wt) {
  int mat = blockIdx.y;              // 0..15: type*4 + layer
  int type = mat >> 2, layer = mat & 3;
  const float* src = (type == 0) ? Wq : (type == 1) ? Wk : (type == 2) ? Wv : Wo;
  src += (long)layer * BD * BD;
  ushort_t* dst = Wt + (long)mat * BD * BD;
  __shared__ float t[32][33];
  int k0 = (blockIdx.x & 7) * 32, n0 = (blockIdx.x >> 3) * 32;
  int tid = threadIdx.x;
  for (int i = tid; i < 1024; i += 256) {
    int kk = i >> 5, nn = i & 31;
    t[kk][nn] = src[(long)(k0 + kk) * BD + n0 + nn];
  }
  __syncthreads();
  for (int i = tid; i < 1024; i += 256) {
    int nn = i >> 5, kk = i & 31;
    dst[(long)(n0 + nn) * BD + k0 + kk] = f2b(t[kk][nn]);
  }
}

// ---------------- G transpose+cast: Ght[b][m][n] = bf16(G[b][n][m]) ----------------
__global__ __launch_bounds__(256) void k_gtrans(const float* __restrict__ G,
                                                ushort_t* __restrict__ Ght) {
  __shared__ ushort_t t[64][65];
  int b = blockIdx.y;
  int m0 = (blockIdx.x & 15) * 64, n0 = (blockIdx.x >> 4) * 64;
  const float* Gb = G + (long)b * NN * NN;
  ushort_t* dst = Ght + (long)b * NN * NN;
  int tid = threadIdx.x;
  #pragma unroll
  for (int rr = 0; rr < 16; rr++) {
    int n = rr * 4 + (tid >> 6);
    int m = tid & 63;
    t[m][n] = f2b(Gb[(long)(n0 + n) * NN + m0 + m]);
  }
  __syncthreads();
  #pragma unroll
  for (int rr = 0; rr < 8; rr++) {
    int m = rr * 8 + (tid >> 5);
    int n2 = (tid & 31) * 2;
    unsigned w = (unsigned)t[m][n2] | ((unsigned)t[m][n2 + 1] << 16);
    *(unsigned*)&dst[(long)(m0 + m) * NN + n0 + n2] = w;
  }
}

// ---------------- sat transpose: satT[b][d][n] = Xh_sat[b][n][d] ----------------
__global__ __launch_bounds__(256) void k_satT(const ushort_t* __restrict__ Xh,
                                              ushort_t* __restrict__ satT) {
  __shared__ ushort_t t[64][65];
  int b = blockIdx.y;
  int n0 = (blockIdx.x & 15) * 64, d0 = (blockIdx.x >> 4) * 64;
  const ushort_t* src = Xh + ((long)b * LQ + 1) * BD;
  ushort_t* dst = satT + (long)b * BD * NN;
  int tid = threadIdx.x;
  #pragma unroll
  for (int rr = 0; rr < 16; rr++) {
    int n = rr * 4 + (tid >> 6);
    int d = tid & 63;
    t[n][d] = src[(long)(n0 + n) * BD + d0 + d];
  }
  __syncthreads();
  #pragma unroll
  for (int rr = 0; rr < 8; rr++) {
    int d = rr * 8 + (tid >> 5);
    int n2 = (tid & 31) * 2;
    unsigned w = (unsigned)t[n2][d] | ((unsigned)t[n2 + 1][d] << 16);
    *(unsigned*)&dst[(long)(d0 + d) * NN + n0 + n2] = w;
  }
}

// ---------------- shared MFMA GEMM core: C[64,64] tile of A[M,256]@W ----------------
static __device__ __forceinline__ void gemm_core(const ushort_t* __restrict__ A,
                                                 const ushort_t* __restrict__ W,
                                                 ushort_t* Ws,
                                                 float* __restrict__ Cf,
                                                 ushort_t* __restrict__ Ch,
                                                 int M, int m0, int n0) {
  int tid = threadIdx.x;
  int wave = tid >> 6, lane = tid & 63;
  int l15 = lane & 15, quad = lane >> 4;
  for (int i = tid; i < 64 * 32; i += 256) {
    int r = i >> 5, c8 = (i & 31) * 8;
    *(uint4*)&Ws[r * 264 + c8] = *(const uint4*)&W[(long)(n0 + r) * 256 + c8];
  }
  __syncthreads();
  int mrow = m0 + wave * 16 + l15;
  if (mrow > M - 1) mrow = M - 1;
  f32x4 acc[4];
  #pragma unroll
  for (int f = 0; f < 4; f++) { acc[f][0] = 0.f; acc[f][1] = 0.f; acc[f][2] = 0.f; acc[f][3] = 0.f; }
  #pragma unroll
  for (int k0 = 0; k0 < 256; k0 += 32) {
    short8 a = *(const short8*)&A[(long)mrow * 256 + k0 + quad * 8];
    #pragma unroll
    for (int f = 0; f < 4; f++) {
      short8 bb = *(const short8*)&Ws[(f * 16 + l15) * 264 + k0 + quad * 8];
      acc[f] = __builtin_amdgcn_mfma_f32_16x16x32_bf16(a, bb, acc[f], 0, 0, 0);
    }
  }
  #pragma unroll
  for (int f = 0; f < 4; f++)
    #pragma unroll
    for (int r = 0; r < 4; r++) {
      int m = m0 + wave * 16 + quad * 4 + r;
      if (m < M) {
        long idx = (long)m * 256 + n0 + f * 16 + l15;
        if (Cf) Cf[idx] = acc[f][r];
        else    Ch[idx] = f2b(acc[f][r]);
      }
    }
}

// fused Q/K/V projection: grid (257, 12)
__global__ __launch_bounds__(256) void gemm_qkv(const ushort_t* __restrict__ Xh,
                                                const ushort_t* __restrict__ Wt, int layer,
                                                ushort_t* __restrict__ Qo,
                                                ushort_t* __restrict__ Ko,
                                                ushort_t* __restrict__ Vo, int M) {
  __shared__ __align__(16) ushort_t Ws[64 * 264];
  int which = blockIdx.y >> 2, n0 = (blockIdx.y & 3) * 64;
  const ushort_t* W = Wt + (long)(which * 4 + layer) * 65536;
  ushort_t* C = (which == 0) ? Qo : (which == 1) ? Ko : Vo;
  gemm_core(Xh, W, Ws, nullptr, C, M, blockIdx.x * 64, n0);
}

// fused relay K/V projection over sat rows: grid (16, 8, NB)
__global__ __launch_bounds__(256) void gemm_kv(const ushort_t* __restrict__ Xh,
                                               const ushort_t* __restrict__ Wt, int layer,
                                               ushort_t* __restrict__ Ko,
                                               ushort_t* __restrict__ Vo) {
  __shared__ __align__(16) ushort_t Ws[64 * 264];
  int which = blockIdx.y >> 2, n0 = (blockIdx.y & 3) * 64;
  int b = blockIdx.z;
  const ushort_t* W = Wt + (long)((which + 1) * 4 + layer) * 65536;
  const ushort_t* A = Xh + (long)b * (LQ * BD) + BD;
  ushort_t* C = ((which == 0) ? Ko : Vo) + (long)b * (NN * BD);
  gemm_core(A, W, Ws, nullptr, C, NN, blockIdx.x * 64, n0);
}

// o-projection, fp32 out: grid (257, 4)
__global__ __launch_bounds__(256) void gemm_oproj(const ushort_t* __restrict__ Oh,
                                                  const ushort_t* __restrict__ Wt, int layer,
                                                  float* __restrict__ Cf, int M) {
  __shared__ __align__(16) ushort_t Ws[64 * 264];
  gemm_core(Oh, Wt + (long)(12 + layer) * 65536, Ws, Cf, nullptr, M,
            blockIdx.x * 64, blockIdx.y * 64);
}

// ---------------- graph mixing: X_sat[b,m,d] = sum_n Ght[b,m,n] * satT[b,d,n] ----------------
__global__ __launch_bounds__(256) void gemm_gtx2(const ushort_t* __restrict__ Ght,
                                                 const ushort_t* __restrict__ satT,
                                                 float* __restrict__ X,
                                                 ushort_t* __restrict__ Xh) {
  int b = blockIdx.z;
  const ushort_t* A = Ght + (long)b * NN * NN;
  const ushort_t* Bp = satT + (long)b * BD * NN;
  int tid = threadIdx.x;
  int wave = tid >> 6, lane = tid & 63;
  int l15 = lane & 15, quad = lane >> 4;
  int m0 = blockIdx.x * 64, d0 = blockIdx.y * 64;
  int arow = m0 + wave * 16 + l15;
  f32x4 acc[4];
  #pragma unroll
  for (int f = 0; f < 4; f++) { acc[f][0] = 0.f; acc[f][1] = 0.f; acc[f][2] = 0.f; acc[f][3] = 0.f; }
  for (int n0 = 0; n0 < NN; n0 += 32) {
    short8 a = *(const short8*)&A[(long)arow * NN + n0 + quad * 8];
    #pragma unroll
    for (int f = 0; f < 4; f++) {
      short8 bb = *(const short8*)&Bp[(long)(d0 + f * 16 + l15) * NN + n0 + quad * 8];
      acc[f] = __builtin_amdgcn_mfma_f32_16x16x32_bf16(a, bb, acc[f], 0, 0, 0);
    }
  }
  long xb = ((long)b * LQ + 1) * 256;
  #pragma unroll
  for (int f = 0; f < 4; f++)
    #pragma unroll
    for (int r = 0; r < 4; r++) {
      int m = m0 + wave * 16 + quad * 4 + r;
      int d = d0 + f * 16 + l15;
      long idx = xb + (long)m * 256 + d;
      X[idx] = acc[f][r];
      Xh[idx] = f2b(acc[f][r]);
    }
}

// ---------------- self attention v2: 32 q-rows/wave, 64-key chunks, exp2 softmax ----------------
// grid (9, NH, NB); block 256 = 4 waves.
__global__ __launch_bounds__(256) void attn_mfma2(const ushort_t* __restrict__ Qh,
                                                  const ushort_t* __restrict__ Kh,
                                                  const ushort_t* __restrict__ Vh,
                                                  ushort_t* __restrict__ Oh) {
  __shared__ __align__(16) ushort_t Ks[2][64][40];   // [buf][key][d]
  __shared__ __align__(16) ushort_t Vt[2][32][72];   // [buf][d][key]
  __shared__ __align__(16) ushort_t Ps[4][32][72];   // per-wave P round-trip
  const float C1 = 0.17677669529663687f * 1.4426950408889634f;  // scale * log2(e)
  int tid = threadIdx.x;
  int wave = tid >> 6, lane = tid & 63;
  int l15 = lane & 15, quad = lane >> 4;
  int h = blockIdx.y, b = blockIdx.z;
  long hb = ((long)b * LQ) * BD + h * DH;
  int q0 = blockIdx.x * 128 + wave * 32;

  short8 qf[2];
  #pragma unroll
  for (int t = 0; t < 2; t++) {
    int qc = q0 + t * 16 + l15;
    if (qc > LQ - 1) qc = LQ - 1;
    qf[t] = *(const short8*)&Qh[hb + (long)qc * BD + quad * 8];
  }
  f32x4 o[2][2];
  float lsum[2][4], mrun[2][4];
  #pragma unroll
  for (int t = 0; t < 2; t++) {
    #pragma unroll
    for (int r = 0; r < 4; r++) { o[t][0][r] = 0.f; o[t][1][r] = 0.f; lsum[t][r] = 0.f; mrun[t][r] = -1e30f; }
  }

  int skr = tid >> 2, skc = (tid & 3) * 8;     // K staging: 64 rows x 4 col-groups of 8
  int svk = tid & 63, svd = (tid >> 6) * 8;    // V staging: key, d-group of 8

  uint4 kreg, vreg;
  uint4 z4u; z4u.x = 0; z4u.y = 0; z4u.z = 0; z4u.w = 0;
  // prologue: stage chunk 0 into buf 0
  {
    int kk = skr;  // chunk 0
    kreg = (kk < LQ) ? *(const uint4*)&Kh[hb + (long)kk * BD + skc] : z4u;
    int vk = svk;
    vreg = (vk < LQ) ? *(const uint4*)&Vh[hb + (long)vk * BD + svd] : z4u;
    *(uint4*)&Ks[0][skr][skc] = kreg;
    const ushort_t* vr = (const ushort_t*)&vreg;
    #pragma unroll
    for (int j = 0; j < 8; j++) Vt[0][svd + j][svk] = vr[j];
  }
  __syncthreads();

  for (int c = 0; c < 17; c++) {
    int pb = c & 1;
    if (c < 16) {  // prefetch next chunk into registers (overlaps compute)
      int kk = (c + 1) * 64 + skr;
      kreg = (kk < LQ) ? *(const uint4*)&Kh[hb + (long)kk * BD + skc] : z4u;
      int vk = (c + 1) * 64 + svk;
      vreg = (vk < LQ) ? *(const uint4*)&Vh[hb + (long)vk * BD + svd] : z4u;
    }
    // ---- QK^T: S[32q x 64k] ----
    short8 bk0 = *(const short8*)&Ks[pb][l15][quad * 8];
    short8 bk1 = *(const short8*)&Ks[pb][16 + l15][quad * 8];
    short8 bk2 = *(const short8*)&Ks[pb][32 + l15][quad * 8];
    short8 bk3 = *(const short8*)&Ks[pb][48 + l15][quad * 8];
    f32x4 zf; zf[0] = 0.f; zf[1] = 0.f; zf[2] = 0.f; zf[3] = 0.f;
    f32x4 s[2][4];
    #pragma unroll
    for (int t = 0; t < 2; t++) {
      s[t][0] = __builtin_amdgcn_mfma_f32_16x16x32_bf16(qf[t], bk0, zf, 0, 0, 0);
      s[t][1] = __builtin_amdgcn_mfma_f32_16x16x32_bf16(qf[t], bk1, zf, 0, 0, 0);
      s[t][2] = __builtin_amdgcn_mfma_f32_16x16x32_bf16(qf[t], bk2, zf, 0, 0, 0);
      s[t][3] = __builtin_amdgcn_mfma_f32_16x16x32_bf16(qf[t], bk3, zf, 0, 0, 0);
    }
    // ---- online softmax (log2 domain) ----
    bool last = (c == 16);
    int kb = c * 64;
    #pragma unroll
    for (int t = 0; t < 2; t++) {
      #pragma unroll
      for (int r = 0; r < 4; r++) {
        float sc[4];
        #pragma unroll
        for (int f = 0; f < 4; f++) sc[f] = s[t][f][r];
        if (last) {
          #pragma unroll
          for (int f = 0; f < 4; f++)
            if (kb + f * 16 + l15 >= LQ) sc[f] = -1e30f;
        }
        float cm = fmaxf(fmaxf(sc[0], sc[1]), fmaxf(sc[2], sc[3]));
        cm = fmaxf(cm, __shfl_xor(cm, 1));
        cm = fmaxf(cm, __shfl_xor(cm, 2));
        cm = fmaxf(cm, __shfl_xor(cm, 4));
        cm = fmaxf(cm, __shfl_xor(cm, 8));
        float mn = fmaxf(mrun[t][r], cm * C1);
        float al = exp2f(mrun[t][r] - mn);
        mrun[t][r] = mn;
        float p[4], ps = 0.f;
        #pragma unroll
        for (int f = 0; f < 4; f++) { p[f] = exp2f(sc[f] * C1 - mn); ps += p[f]; }
        lsum[t][r] = lsum[t][r] * al + ps;
        o[t][0][r] *= al; o[t][1][r] *= al;
        int prow = t * 16 + quad * 4 + r;
        #pragma unroll
        for (int f = 0; f < 4; f++) Ps[wave][prow][f * 16 + l15] = f2b(p[f]);
      }
    }
    // ---- PV (Ps is wave-private: no barrier) ----
    short8 vb00 = *(const short8*)&Vt[pb][l15][quad * 8];
    short8 vb01 = *(const short8*)&Vt[pb][l15][32 + quad * 8];
    short8 vb10 = *(const short8*)&Vt[pb][16 + l15][quad * 8];
    short8 vb11 = *(const short8*)&Vt[pb][16 + l15][32 + quad * 8];
    #pragma unroll
    for (int t = 0; t < 2; t++) {
      short8 pa0 = *(const short8*)&Ps[wave][t * 16 + l15][quad * 8];
      short8 pa1 = *(const short8*)&Ps[wave][t * 16 + l15][32 + quad * 8];
      o[t][0] = __builtin_amdgcn_mfma_f32_16x16x32_bf16(pa0, vb00, o[t][0], 0, 0, 0);
      o[t][0] = __builtin_amdgcn_mfma_f32_16x16x32_bf16(pa1, vb01, o[t][0], 0, 0, 0);
      o[t][1] = __builtin_amdgcn_mfma_f32_16x16x32_bf16(pa0, vb10, o[t][1], 0, 0, 0);
      o[t][1] = __builtin_amdgcn_mfma_f32_16x16x32_bf16(pa1, vb11, o[t][1], 0, 0, 0);
    }
    if (c < 16) {  // store prefetched chunk into the other buffer
      int nb = 1 - pb;
      *(uint4*)&Ks[nb][skr][skc] = kreg;
      const ushort_t* vr = (const ushort_t*)&vreg;
      #pragma unroll
      for (int j = 0; j < 8; j++) Vt[nb][svd + j][svk] = vr[j];
    }
    __syncthreads();
  }

  #pragma unroll
  for (int t = 0; t < 2; t++)
    #pragma unroll
    for (int r = 0; r < 4; r++) {
      float sv = lsum[t][r];
      sv += __shfl_xor(sv, 1); sv += __shfl_xor(sv, 2);
      sv += __shfl_xor(sv, 4); sv += __shfl_xor(sv, 8);
      float inv = 1.f / sv;
      int row = q0 + t * 16 + quad * 4 + r;
      if (row < LQ) {
        Oh[hb + (long)row * BD + l15] = f2b(o[t][0][r] * inv);
        Oh[hb + (long)row * BD + 16 + l15] = f2b(o[t][1][r] * inv);
      }
    }
}

// ---------------- relay attention: Lq=1, Lk=1024, bf16 K/V ----------------
__global__ __launch_bounds__(256) void attn_relay(const float* __restrict__ q,
                                                  const ushort_t* __restrict__ K,
                                                  const ushort_t* __restrict__ V,
                                                  float* __restrict__ o) {
  int b = blockIdx.x, h = blockIdx.y;
  int tid = threadIdx.x;
  const float scale = 0.17677669529663687f;
  __shared__ float s[NN];
  __shared__ float qs[DH];
  __shared__ float rbuf[256];
  __shared__ float part[8][33];
  if (tid < DH) qs[tid] = q[(long)b * BD + h * DH + tid];
  __syncthreads();
  long base = ((long)b * NN) * BD + h * DH;
  for (int k = tid; k < NN; k += 256) {
    float dot = 0.f;
    const ushort_t* kr = &K[base + (long)k * BD];
    #pragma unroll
    for (int d2 = 0; d2 < 16; d2++) {
      unsigned w = *(const unsigned*)&kr[d2 * 2];
      dot += qs[d2 * 2] * b2f((ushort_t)(w & 0xffff)) + qs[d2 * 2 + 1] * b2f((ushort_t)(w >> 16));
    }
    s[k] = dot * scale;
  }
  __syncthreads();
  float m = -1e30f;
  for (int k = tid; k < NN; k += 256) m = fmaxf(m, s[k]);
  rbuf[tid] = m;
  __syncthreads();
  for (int st = 128; st > 0; st >>= 1) {
    if (tid < st) rbuf[tid] = fmaxf(rbuf[tid], rbuf[tid + st]);
    __syncthreads();
  }
  float mx = rbuf[0];
  __syncthreads();
  float sm = 0.f;
  for (int k = tid; k < NN; k += 256) {
    float p = __expf(s[k] - mx);
    s[k] = p;
    sm += p;
  }
  rbuf[tid] = sm;
  __syncthreads();
  for (int st = 128; st > 0; st >>= 1) {
    if (tid < st) rbuf[tid] += rbuf[tid + st];
    __syncthreads();
  }
  float inv = 1.f / rbuf[0];
  int d = tid & 31, slice = tid >> 5;
  float acc = 0.f;
  for (int k = slice; k < NN; k += 8) acc += s[k] * b2f(V[base + (long)k * BD + d]);
  part[slice][d] = acc;
  __syncthreads();
  if (tid < DH) {
    float ss = 0.f;
    #pragma unroll
    for (int t = 0; t < 8; t++) ss += part[t][tid];
    o[(long)b * BD + h * DH + tid] = ss * inv;
  }
}

// ---------------- relay row ops (fp32 weights; tiny) ----------------
__global__ __launch_bounds__(256) void rowvec_matmul(const float* __restrict__ X, long xstride,
                                                     const float* __restrict__ W,
                                                     float* __restrict__ out) {
  int b = blockIdx.x, tid = threadIdx.x;
  __shared__ float xs[BD];
  xs[tid] = X[(long)b * xstride + tid];
  __syncthreads();
  float acc = 0.f;
  for (int k = 0; k < BD; k++) acc += xs[k] * W[(long)k * BD + tid];
  out[(long)b * BD + tid] = acc;
}

__global__ __launch_bounds__(256) void rowvec_oproj_ln(const float* __restrict__ o,
                                                       const float* __restrict__ Wo,
                                                       const float* __restrict__ Xres, long xstride,
                                                       const float* __restrict__ g,
                                                       const float* __restrict__ beta,
                                                       float* __restrict__ dst, long dstride,
                                                       ushort_t* __restrict__ dsth, long dhstride) {
  int b = blockIdx.x, tid = threadIdx.x;
  __shared__ float xs[BD];
  __shared__ float rs[256], rq[256];
  xs[tid] = o[(long)b * BD + tid];
  __syncthreads();
  float acc = 0.f;
  for (int k = 0; k < BD; k++) acc += xs[k] * Wo[(long)k * BD + tid];
  float v = acc + Xres[(long)b * xstride + tid];
  rs[tid] = v;
  rq[tid] = v * v;
  __syncthreads();
  for (int st = 128; st > 0; st >>= 1) {
    if (tid < st) { rs[tid] += rs[tid + st]; rq[tid] += rq[tid + st]; }
    __syncthreads();
  }
  float mu = rs[0] * (1.f / BD);
  float var = rq[0] * (1.f / BD) - mu * mu;
  float y = (v - mu) * rsqrtf(var + EPSV) * g[tid] + beta[tid];
  dst[(long)b * dstride + tid] = y;
  if (dsth) dsth[(long)b * dhstride + tid] = f2b(y);
}

__global__ __launch_bounds__(256) void ln_residual(const float* __restrict__ OP,
                                                   float* __restrict__ X,
                                                   ushort_t* __restrict__ Xh,
                                                   const float* __restrict__ g,
                                                   const float* __restrict__ beta) {
  long r = blockIdx.x;
  int tid = threadIdx.x;
  __shared__ float rs[256], rq[256];
  float v = OP[r * BD + tid] + X[r * BD + tid];
  rs[tid] = v;
  rq[tid] = v * v;
  __syncthreads();
  for (int st = 128; st > 0; st >>= 1) {
    if (tid < st) { rs[tid] += rs[tid + st]; rq[tid] += rq[tid + st]; }
    __syncthreads();
  }
  float mu = rs[0] * (1.f / BD);
  float var = rq[0] * (1.f / BD) - mu * mu;
  float y = (v - mu) * rsqrtf(var + EPSV) * g[tid] + beta[tid];
  X[r * BD + tid] = y;
  Xh[r * BD + tid] = f2b(y);
}

// ---------------- launch ----------------
extern "C" void kernel_launch(void* const* d_in, const int* in_sizes, int n_in,
                              void* d_out, int out_size, void* d_ws, size_t ws_size,
                              hipStream_t stream) {
  const float* gv    = (const float*)d_in[0];
  const float* graph = (const float*)d_in[1];
  const float* Wq    = (const float*)d_in[2];
  const float* Wk    = (const float*)d_in[3];
  const float* Wv    = (const float*)d_in[4];
  const float* Wo    = (const float*)d_in[5];
  const float* lg    = (const float*)d_in[6];
  const float* lb    = (const float*)d_in[7];
  float* out = (float*)d_out;

  const long S  = (long)NB * LQ * BD;   // 4,198,400
  const long S4 = S * 4, S2 = S * 2;
  char* base = (char*)d_ws;
  // layout: X(S4) | Xh(S2) | B1(S4) | Qh(S2) | Kh(S2) | Vh(S2) | Oh(S2) | Wt(2MB) | qrel/orel
  // aliases: Ght (32MB) overlays B1+Qh+Kh (33.6MB); satT (8MB) overlays Vh (8.4MB);
  // both live only between relay-0 and layer-1.
  float*    X    = (float*)base;
  ushort_t* Xh   = (ushort_t*)(base + S4);
  float*    B1   = (float*)(base + S4 + S2);
  ushort_t* Qh   = (ushort_t*)(base + 2 * S4 + S2);
  ushort_t* Kh   = (ushort_t*)(base + 2 * S4 + 2 * S2);
  ushort_t* Vh   = (ushort_t*)(base + 2 * S4 + 3 * S2);
  ushort_t* Oh   = (ushort_t*)(base + 2 * S4 + 4 * S2);
  ushort_t* Wt   = (ushort_t*)(base + 2 * S4 + 5 * S2);
  float*    qrel = (float*)(base + 2 * S4 + 5 * S2 + 16L * 65536 * 2);
  float*    orel = qrel + (long)NB * BD;
  ushort_t* Ght  = (ushort_t*)B1;
  ushort_t* satT = Vh;

  const long WSZ = (long)BD * BD;
  const long XST = (long)LQ * BD;
  dim3 blk(256);

  k_copy_cast<<<dim3(2048), blk, 0, stream>>>(gv, X, Xh, S);
  k_wtrans<<<dim3(64, 16), blk, 0, stream>>>(Wq, Wk, Wv, Wo, Wt);

  // ---- layer 0: relay GAT ----
  rowvec_matmul<<<dim3(NB), blk, 0, stream>>>(X, XST, Wq + 0 * WSZ, qrel);
  gemm_kv<<<dim3(16, 8, NB), blk, 0, stream>>>(Xh, Wt, 0, Kh, Vh);
  attn_relay<<<dim3(NB, NH), blk, 0, stream>>>(qrel, Kh, Vh, orel);
  rowvec_oproj_ln<<<dim3(NB), blk, 0, stream>>>(orel, Wo + 0 * WSZ, X, XST,
                                                lg + 0 * BD, lb + 0 * BD, X, XST, Xh, XST);

  // ---- sat mixing: sat = G^T @ sat (pre-transposed MFMA) ----
  k_gtrans<<<dim3(256, NB), blk, 0, stream>>>(graph, Ght);
  k_satT<<<dim3(64, NB), blk, 0, stream>>>(Xh, satT);
  gemm_gtx2<<<dim3(16, 4, NB), blk, 0, stream>>>(Ght, satT, X, Xh);

  // ---- layers 1,2: self GAT ----
  for (int l = 1; l <= 2; l++) {
    gemm_qkv<<<dim3(257, 12), blk, 0, stream>>>(Xh, Wt, l, Qh, Kh, Vh, NB * LQ);
    attn_mfma2<<<dim3(9, NH, NB), blk, 0, stream>>>(Qh, Kh, Vh, Oh);
    gemm_oproj<<<dim3(257, 4), blk, 0, stream>>>(Oh, Wt, l, B1, NB * LQ);
    ln_residual<<<dim3(NB * LQ), blk, 0, stream>>>(B1, X, Xh, lg + l * BD, lb + l * BD);
  }

  // ---- sat_u output ----
  k_sat_out<<<dim3(2048), blk, 0, stream>>>(X, out + (long)NB * BD);

  // ---- layer 3: final relay GAT -> z ----
  rowvec_matmul<<<dim3(NB), blk, 0, stream>>>(X, XST, Wq + 3 * WSZ, qrel);
  gemm_kv<<<dim3(16, 8, NB), blk, 0, stream>>>(Xh, Wt, 3, Kh, Vh);
  attn_relay<<<dim3(NB, NH), blk, 0, stream>>>(qrel, Kh, Vh, orel);
  rowvec_oproj_ln<<<dim3(NB), blk, 0, stream>>>(orel, Wo + 3 * WSZ, X, XST,
                                                lg + 3 * BD, lb + 3 * BD, out, BD, nullptr, 0);
}

// Round 9
// 721.928 us; speedup vs baseline: 1.0483x; 1.0483x over previous
//
#include <hip/hip_runtime.h>
#include <hip/hip_bf16.h>
#include <math.h>

#define BD   256    // D
#define NH   8      // heads
#define DH   32     // head dim
#define NB   16     // batch
#define NN   1024   // N
#define LQ   1025   // N+1
#define EPSV 1e-5f
#define KP   1088   // padded key stride for VhT (17*64)
#define MST  1152   // Mrow row stride (>= 9*128)

typedef unsigned short ushort_t;
typedef __attribute__((ext_vector_type(8))) short short8;
typedef __attribute__((ext_vector_type(4))) float f32x4;

static __device__ __forceinline__ ushort_t f2b(float x) {
  union { __hip_bfloat16 h; ushort_t u; } cv;
  cv.h = __float2bfloat16(x);
  return cv.u;
}
static __device__ __forceinline__ float b2f(ushort_t u) {
  union { float f; unsigned v; } c; c.v = ((unsigned)u) << 16; return c.f;
}

// ---------------- copy / cast helpers ----------------
__global__ void k_copy_cast(const float* __restrict__ in, float* __restrict__ X,
                            ushort_t* __restrict__ Xh, long n) {
  long stride = (long)gridDim.x * 256;
  for (long i = (long)blockIdx.x * 256 + threadIdx.x; i < n; i += stride) {
    float v = in[i];
    X[i] = v;
    Xh[i] = f2b(v);
  }
}

__global__ void k_sat_out(const float* __restrict__ X, float* __restrict__ out) {
  long n = (long)NB * NN * BD;
  long stride = (long)gridDim.x * 256;
  for (long i = (long)blockIdx.x * 256 + threadIdx.x; i < n; i += stride) {
    long b = i / ((long)NN * BD);
    long r = i - b * ((long)NN * BD);
    out[i] = X[b * (long)LQ * BD + BD + r];
  }
}

// ---------------- weight transpose+cast: Wt[slot][n][k] = bf16(W[k][n]) ----------------
__global__ __launch_bounds__(256) void k_wtrans(const float* __restrict__ Wq,
                                                const float* __restrict__ Wk,
                                                const float* __restrict__ Wv,
                                                const float* __restrict__ Wo,
                                                ushort_t* __restrict__ Wt) {
  int mat = blockIdx.y;              // 0..15: type*4 + layer
  int type = mat >> 2, layer = mat & 3;
  const float* src = (type == 0) ? Wq : (type == 1) ? Wk : (type == 2) ? Wv : Wo;
  src += (long)layer * BD * BD;
  ushort_t* dst = Wt + (long)mat * BD * BD;
  __shared__ float t[32][33];
  int k0 = (blockIdx.x & 7) * 32, n0 = (blockIdx.x >> 3) * 32;
  int tid = threadIdx.x;
  for (int i = tid; i < 1024; i += 256) {
    int kk = i >> 5, nn = i & 31;
    t[kk][nn] = src[(long)(k0 + kk) * BD + n0 + nn];
  }
  __syncthreads();
  for (int i = tid; i < 1024; i += 256) {
    int nn = i >> 5, kk = i & 31;
    dst[(long)(n0 + nn) * BD + k0 + kk] = f2b(t[kk][nn]);
  }
}

// ---------------- G transpose+cast: Ght[b][m][n] = bf16(G[b][n][m]) ----------------
__global__ __launch_bounds__(256) void k_gtrans(const float* __restrict__ G,
                                                ushort_t* __restrict__ Ght) {
  __shared__ ushort_t t[64][65];
  int b = blockIdx.y;
  int m0 = (blockIdx.x & 15) * 64, n0 = (blockIdx.x >> 4) * 64;
  const float* Gb = G + (long)b * NN * NN;
  ushort_t* dst = Ght + (long)b * NN * NN;
  int tid = threadIdx.x;
  #pragma unroll
  for (int rr = 0; rr < 16; rr++) {
    int n = rr * 4 + (tid >> 6);
    int m = tid & 63;
    t[m][n] = f2b(Gb[(long)(n0 + n) * NN + m0 + m]);
  }
  __syncthreads();
  #pragma unroll
  for (int rr = 0; rr < 8; rr++) {
    int m = rr * 8 + (tid >> 5);
    int n2 = (tid & 31) * 2;
    unsigned w = (unsigned)t[m][n2] | ((unsigned)t[m][n2 + 1] << 16);
    *(unsigned*)&dst[(long)(m0 + m) * NN + n0 + n2] = w;
  }
}

// ---------------- sat transpose: satT[b][d][n] = Xh_sat[b][n][d] ----------------
__global__ __launch_bounds__(256) void k_satT(const ushort_t* __restrict__ Xh,
                                              ushort_t* __restrict__ satT) {
  __shared__ ushort_t t[64][65];
  int b = blockIdx.y;
  int n0 = (blockIdx.x & 15) * 64, d0 = (blockIdx.x >> 4) * 64;
  const ushort_t* src = Xh + ((long)b * LQ + 1) * BD;
  ushort_t* dst = satT + (long)b * BD * NN;
  int tid = threadIdx.x;
  #pragma unroll
  for (int rr = 0; rr < 16; rr++) {
    int n = rr * 4 + (tid >> 6);
    int d = tid & 63;
    t[n][d] = src[(long)(n0 + n) * BD + d0 + d];
  }
  __syncthreads();
  #pragma unroll
  for (int rr = 0; rr < 8; rr++) {
    int d = rr * 8 + (tid >> 5);
    int n2 = (tid & 31) * 2;
    unsigned w = (unsigned)t[n2][d] | ((unsigned)t[n2 + 1][d] << 16);
    *(unsigned*)&dst[(long)(d0 + d) * NN + n0 + n2] = w;
  }
}

// ---------------- V transpose: VhT[b][d][key(KP)] = Vh[b*LQ+key][d], zero-padded ----------------
__global__ __launch_bounds__(256) void k_vtrans(const ushort_t* __restrict__ Vh,
                                                ushort_t* __restrict__ VhT) {
  __shared__ ushort_t t[64][65];
  int b = blockIdx.z;
  int n0 = blockIdx.x * 64, d0 = blockIdx.y * 64;
  const ushort_t* src = Vh + (long)b * LQ * BD;
  ushort_t* dst = VhT + (long)b * BD * KP;
  int tid = threadIdx.x;
  #pragma unroll
  for (int rr = 0; rr < 16; rr++) {
    int n = rr * 4 + (tid >> 6);
    int d = tid & 63;
    int key = n0 + n;
    t[n][d] = (key < LQ) ? src[(long)key * BD + d0 + d] : (ushort_t)0;
  }
  __syncthreads();
  #pragma unroll
  for (int rr = 0; rr < 8; rr++) {
    int d = rr * 8 + (tid >> 5);
    int n2 = (tid & 31) * 2;
    unsigned w = (unsigned)t[n2][d] | ((unsigned)t[n2 + 1][d] << 16);
    *(unsigned*)&dst[(long)(d0 + d) * KP + n0 + n2] = w;
  }
}

// ---------------- shared MFMA GEMM core: C[64,64] tile of A[M,256]@W ----------------
static __device__ __forceinline__ void gemm_core(const ushort_t* __restrict__ A,
                                                 const ushort_t* __restrict__ W,
                                                 ushort_t* Ws,
                                                 float* __restrict__ Cf,
                                                 ushort_t* __restrict__ Ch,
                                                 int M, int m0, int n0) {
  int tid = threadIdx.x;
  int wave = tid >> 6, lane = tid & 63;
  int l15 = lane & 15, quad = lane >> 4;
  for (int i = tid; i < 64 * 32; i += 256) {
    int r = i >> 5, c8 = (i & 31) * 8;
    *(uint4*)&Ws[r * 264 + c8] = *(const uint4*)&W[(long)(n0 + r) * 256 + c8];
  }
  __syncthreads();
  int mrow = m0 + wave * 16 + l15;
  if (mrow > M - 1) mrow = M - 1;
  f32x4 acc[4];
  #pragma unroll
  for (int f = 0; f < 4; f++) { acc[f][0] = 0.f; acc[f][1] = 0.f; acc[f][2] = 0.f; acc[f][3] = 0.f; }
  #pragma unroll
  for (int k0 = 0; k0 < 256; k0 += 32) {
    short8 a = *(const short8*)&A[(long)mrow * 256 + k0 + quad * 8];
    #pragma unroll
    for (int f = 0; f < 4; f++) {
      short8 bb = *(const short8*)&Ws[(f * 16 + l15) * 264 + k0 + quad * 8];
      acc[f] = __builtin_amdgcn_mfma_f32_16x16x32_bf16(a, bb, acc[f], 0, 0, 0);
    }
  }
  #pragma unroll
  for (int f = 0; f < 4; f++)
    #pragma unroll
    for (int r = 0; r < 4; r++) {
      int m = m0 + wave * 16 + quad * 4 + r;
      if (m < M) {
        long idx = (long)m * 256 + n0 + f * 16 + l15;
        if (Cf) Cf[idx] = acc[f][r];
        else    Ch[idx] = f2b(acc[f][r]);
      }
    }
}

// fused Q/K/V projection: grid (257, 12)
__global__ __launch_bounds__(256) void gemm_qkv(const ushort_t* __restrict__ Xh,
                                                const ushort_t* __restrict__ Wt, int layer,
                                                ushort_t* __restrict__ Qo,
                                                ushort_t* __restrict__ Ko,
                                                ushort_t* __restrict__ Vo, int M) {
  __shared__ __align__(16) ushort_t Ws[64 * 264];
  int which = blockIdx.y >> 2, n0 = (blockIdx.y & 3) * 64;
  const ushort_t* W = Wt + (long)(which * 4 + layer) * 65536;
  ushort_t* C = (which == 0) ? Qo : (which == 1) ? Ko : Vo;
  gemm_core(Xh, W, Ws, nullptr, C, M, blockIdx.x * 64, n0);
}

// fused relay K/V projection over sat rows: grid (16, 8, NB)
__global__ __launch_bounds__(256) void gemm_kv(const ushort_t* __restrict__ Xh,
                                               const ushort_t* __restrict__ Wt, int layer,
                                               ushort_t* __restrict__ Ko,
                                               ushort_t* __restrict__ Vo) {
  __shared__ __align__(16) ushort_t Ws[64 * 264];
  int which = blockIdx.y >> 2, n0 = (blockIdx.y & 3) * 64;
  int b = blockIdx.z;
  const ushort_t* W = Wt + (long)((which + 1) * 4 + layer) * 65536;
  const ushort_t* A = Xh + (long)b * (LQ * BD) + BD;
  ushort_t* C = ((which == 0) ? Ko : Vo) + (long)b * (NN * BD);
  gemm_core(A, W, Ws, nullptr, C, NN, blockIdx.x * 64, n0);
}

// o-projection, fp32 out: grid (257, 4)
__global__ __launch_bounds__(256) void gemm_oproj(const ushort_t* __restrict__ Oh,
                                                  const ushort_t* __restrict__ Wt, int layer,
                                                  float* __restrict__ Cf, int M) {
  __shared__ __align__(16) ushort_t Ws[64 * 264];
  gemm_core(Oh, Wt + (long)(12 + layer) * 65536, Ws, Cf, nullptr, M,
            blockIdx.x * 64, blockIdx.y * 64);
}

// ---------------- graph mixing: X_sat[b,m,d] = sum_n Ght[b,m,n] * satT[b,d,n] ----------------
__global__ __launch_bounds__(256) void gemm_gtx2(const ushort_t* __restrict__ Ght,
                                                 const ushort_t* __restrict__ satT,
                                                 float* __restrict__ X,
                                                 ushort_t* __restrict__ Xh) {
  int b = blockIdx.z;
  const ushort_t* A = Ght + (long)b * NN * NN;
  const ushort_t* Bp = satT + (long)b * BD * NN;
  int tid = threadIdx.x;
  int wave = tid >> 6, lane = tid & 63;
  int l15 = lane & 15, quad = lane >> 4;
  int m0 = blockIdx.x * 64, d0 = blockIdx.y * 64;
  int arow = m0 + wave * 16 + l15;
  f32x4 acc[4];
  #pragma unroll
  for (int f = 0; f < 4; f++) { acc[f][0] = 0.f; acc[f][1] = 0.f; acc[f][2] = 0.f; acc[f][3] = 0.f; }
  for (int n0 = 0; n0 < NN; n0 += 32) {
    short8 a = *(const short8*)&A[(long)arow * NN + n0 + quad * 8];
    #pragma unroll
    for (int f = 0; f < 4; f++) {
      short8 bb = *(const short8*)&Bp[(long)(d0 + f * 16 + l15) * NN + n0 + quad * 8];
      acc[f] = __builtin_amdgcn_mfma_f32_16x16x32_bf16(a, bb, acc[f], 0, 0, 0);
    }
  }
  long xb = ((long)b * LQ + 1) * 256;
  #pragma unroll
  for (int f = 0; f < 4; f++)
    #pragma unroll
    for (int r = 0; r < 4; r++) {
      int m = m0 + wave * 16 + quad * 4 + r;
      int d = d0 + f * 16 + l15;
      long idx = xb + (long)m * 256 + d;
      X[idx] = acc[f][r];
      Xh[idx] = f2b(acc[f][r]);
    }
}

// ---------------- exact row-max pre-pass: Mrow[(b*NH+h)*MST + q] = max_k(q.k) * C1 ----------
// S^T orientation; K row index CLAMPED to <= 1024 (duplicates cannot raise the max -> exact).
__global__ __launch_bounds__(256) void attn_rowmax(const ushort_t* __restrict__ Qh,
                                                   const ushort_t* __restrict__ Kh,
                                                   float* __restrict__ Mrow) {
  const float C1 = 0.17677669529663687f * 1.4426950408889634f;
  int tid = threadIdx.x;
  int wave = tid >> 6, lane = tid & 63;
  int l15 = lane & 15, quad = lane >> 4;
  int h = blockIdx.y, b = blockIdx.z;
  long hb = ((long)b * LQ) * BD + h * DH;
  int q0 = blockIdx.x * 128 + wave * 32;
  short8 qB[2];
  #pragma unroll
  for (int t = 0; t < 2; t++) {
    int qc = q0 + t * 16 + l15; if (qc > LQ - 1) qc = LQ - 1;
    qB[t] = *(const short8*)&Qh[hb + (long)qc * BD + quad * 8];
  }
  float run0 = -3e38f, run1 = -3e38f;
  f32x4 zf; zf[0] = 0.f; zf[1] = 0.f; zf[2] = 0.f; zf[3] = 0.f;
  for (int c = 0; c < 17; c++) {
    int kb = c * 64;
    #pragma unroll
    for (int kt = 0; kt < 4; kt++) {
      int kc = kb + kt * 16 + l15; if (kc > LQ - 1) kc = LQ - 1;
      short8 ka = *(const short8*)&Kh[hb + (long)kc * BD + quad * 8];
      f32x4 s0 = __builtin_amdgcn_mfma_f32_16x16x32_bf16(ka, qB[0], zf, 0, 0, 0);
      f32x4 s1 = __builtin_amdgcn_mfma_f32_16x16x32_bf16(ka, qB[1], zf, 0, 0, 0);
      #pragma unroll
      for (int r = 0; r < 4; r++) {
        run0 = fmaxf(run0, s0[r]);
        run1 = fmaxf(run1, s1[r]);
      }
    }
  }
  run0 = fmaxf(run0, __shfl_xor(run0, 16));
  run0 = fmaxf(run0, __shfl_xor(run0, 32));
  run1 = fmaxf(run1, __shfl_xor(run1, 16));
  run1 = fmaxf(run1, __shfl_xor(run1, 32));
  if (lane < 16) {
    long mb = ((long)b * NH + h) * MST;
    Mrow[mb + q0 + lane] = run0 * C1;
    Mrow[mb + q0 + 16 + lane] = run1 * C1;
  }
}

// ---------------- attention: S^T MFMA, direct-global K/V frags ----------------
// grid (9, NH, NB); block 256 = 4 waves, 32 q/wave. Exact max (Mrow) -> p<=1, lsum>=1.
// K row index clamped <= 1024; keys > 1024 masked by explicit index in the last chunk
// (clamped duplicate rows MUST be masked or key-1024 would be over-weighted).
__global__ __launch_bounds__(256) void attn_fa(const ushort_t* __restrict__ Qh,
                                               const ushort_t* __restrict__ Kh,
                                               const ushort_t* __restrict__ VhT,
                                               const float* __restrict__ Mrow,
                                               ushort_t* __restrict__ Oh) {
  __shared__ __align__(16) ushort_t Ps[4][32][72];
  __shared__ __align__(16) float Lbuf[4][32];
  const float C1 = 0.17677669529663687f * 1.4426950408889634f;
  int tid = threadIdx.x;
  int wave = tid >> 6, lane = tid & 63;
  int l15 = lane & 15, quad = lane >> 4;
  int h = blockIdx.y, b = blockIdx.z;
  long hb = ((long)b * LQ) * BD + h * DH;
  long vB = (long)b * BD * KP;
  int hd0 = h * DH;
  int q0 = blockIdx.x * 128 + wave * 32;

  short8 qB[2];
  float mq[2];
  #pragma unroll
  for (int t = 0; t < 2; t++) {
    int qc = q0 + t * 16 + l15; if (qc > LQ - 1) qc = LQ - 1;
    qB[t] = *(const short8*)&Qh[hb + (long)qc * BD + quad * 8];
    mq[t] = Mrow[((long)b * NH + h) * MST + qc];
  }
  f32x4 o[2][2];
  #pragma unroll
  for (int mt = 0; mt < 2; mt++)
    #pragma unroll
    for (int dt = 0; dt < 2; dt++) { o[mt][dt][0] = 0.f; o[mt][dt][1] = 0.f; o[mt][dt][2] = 0.f; o[mt][dt][3] = 0.f; }
  float ls[2] = {0.f, 0.f};
  f32x4 zf; zf[0] = 0.f; zf[1] = 0.f; zf[2] = 0.f; zf[3] = 0.f;

  for (int c = 0; c < 17; c++) {
    int kb = c * 64;
    bool mstep = (c == 16);
    short8 ka[4], vb[2][2];
    #pragma unroll
    for (int kt = 0; kt < 4; kt++) {
      int kc = kb + kt * 16 + l15; if (kc > LQ - 1) kc = LQ - 1;
      ka[kt] = *(const short8*)&Kh[hb + (long)kc * BD + quad * 8];
    }
    #pragma unroll
    for (int ks = 0; ks < 2; ks++)
      #pragma unroll
      for (int dt = 0; dt < 2; dt++)
        vb[ks][dt] = *(const short8*)&VhT[vB + (long)(hd0 + dt * 16 + l15) * KP + kb + ks * 32 + quad * 8];
    // QK^T (S^T tiles: rows=keys, cols=q)
    f32x4 s[2][4];
    #pragma unroll
    for (int kt = 0; kt < 4; kt++) {
      s[0][kt] = __builtin_amdgcn_mfma_f32_16x16x32_bf16(ka[kt], qB[0], zf, 0, 0, 0);
      s[1][kt] = __builtin_amdgcn_mfma_f32_16x16x32_bf16(ka[kt], qB[1], zf, 0, 0, 0);
    }
    // softmax: p = exp2(s*C1 - m), m exact -> p <= 1
    #pragma unroll
    for (int t = 0; t < 2; t++) {
      #pragma unroll
      for (int kt = 0; kt < 4; kt++) {
        ushort_t pu[4];
        #pragma unroll
        for (int r = 0; r < 4; r++) {
          int key = kb + kt * 16 + quad * 4 + r;
          float sc = s[t][kt][r] * C1 - mq[t];
          if (mstep && key >= LQ) sc = -1e30f;
          float p = exp2f(sc);
          ls[t] += p;
          pu[r] = f2b(p);
        }
        unsigned lo = (unsigned)pu[0] | ((unsigned)pu[1] << 16);
        unsigned hi = (unsigned)pu[2] | ((unsigned)pu[3] << 16);
        uint2 w; w.x = lo; w.y = hi;
        *(uint2*)&Ps[wave][t * 16 + l15][kt * 16 + quad * 4] = w;
      }
    }
    // PV: o[q][d] += P[q][keys] * V[keys][d]  (Ps wave-private)
    #pragma unroll
    for (int ks = 0; ks < 2; ks++) {
      short8 pa0 = *(const short8*)&Ps[wave][l15][ks * 32 + quad * 8];
      short8 pa1 = *(const short8*)&Ps[wave][16 + l15][ks * 32 + quad * 8];
      #pragma unroll
      for (int dt = 0; dt < 2; dt++) {
        o[0][dt] = __builtin_amdgcn_mfma_f32_16x16x32_bf16(pa0, vb[ks][dt], o[0][dt], 0, 0, 0);
        o[1][dt] = __builtin_amdgcn_mfma_f32_16x16x32_bf16(pa1, vb[ks][dt], o[1][dt], 0, 0, 0);
      }
    }
  }
  // denominator: reduce quad-copies, publish via LDS with a full barrier
  #pragma unroll
  for (int t = 0; t < 2; t++) {
    ls[t] += __shfl_xor(ls[t], 16);
    ls[t] += __shfl_xor(ls[t], 32);
  }
  if (quad == 0) {
    Lbuf[wave][l15] = ls[0];
    Lbuf[wave][16 + l15] = ls[1];
  }
  __syncthreads();
  #pragma unroll
  for (int mt = 0; mt < 2; mt++) {
    f32x4 lv = *(const f32x4*)&Lbuf[wave][mt * 16 + quad * 4];
    #pragma unroll
    for (int r = 0; r < 4; r++) {
      int row = q0 + mt * 16 + quad * 4 + r;
      if (row < LQ) {
        float den = lv[r];
        float inv = (den > 0.f) ? 1.f / den : 0.f;
        #pragma unroll
        for (int dt = 0; dt < 2; dt++)
          Oh[hb + (long)row * BD + dt * 16 + l15] = f2b(o[mt][dt][r] * inv);
      }
    }
  }
}

// ---------------- relay attention: Lq=1, Lk=1024, bf16 K/V ----------------
__global__ __launch_bounds__(256) void attn_relay(const float* __restrict__ q,
                                                  const ushort_t* __restrict__ K,
                                                  const ushort_t* __restrict__ V,
                                                  float* __restrict__ o) {
  int b = blockIdx.x, h = blockIdx.y;
  int tid = threadIdx.x;
  const float scale = 0.17677669529663687f;
  __shared__ float s[NN];
  __shared__ float qs[DH];
  __shared__ float rbuf[256];
  __shared__ float part[8][33];
  if (tid < DH) qs[tid] = q[(long)b * BD + h * DH + tid];
  __syncthreads();
  long base = ((long)b * NN) * BD + h * DH;
  for (int k = tid; k < NN; k += 256) {
    float dot = 0.f;
    const ushort_t* kr = &K[base + (long)k * BD];
    #pragma unroll
    for (int d2 = 0; d2 < 16; d2++) {
      unsigned w = *(const unsigned*)&kr[d2 * 2];
      dot += qs[d2 * 2] * b2f((ushort_t)(w & 0xffff)) + qs[d2 * 2 + 1] * b2f((ushort_t)(w >> 16));
    }
    s[k] = dot * scale;
  }
  __syncthreads();
  float m = -1e30f;
  for (int k = tid; k < NN; k += 256) m = fmaxf(m, s[k]);
  rbuf[tid] = m;
  __syncthreads();
  for (int st = 128; st > 0; st >>= 1) {
    if (tid < st) rbuf[tid] = fmaxf(rbuf[tid], rbuf[tid + st]);
    __syncthreads();
  }
  float mx = rbuf[0];
  __syncthreads();
  float sm = 0.f;
  for (int k = tid; k < NN; k += 256) {
    float p = __expf(s[k] - mx);
    s[k] = p;
    sm += p;
  }
  rbuf[tid] = sm;
  __syncthreads();
  for (int st = 128; st > 0; st >>= 1) {
    if (tid < st) rbuf[tid] += rbuf[tid + st];
    __syncthreads();
  }
  float inv = 1.f / rbuf[0];
  int d = tid & 31, slice = tid >> 5;
  float acc = 0.f;
  for (int k = slice; k < NN; k += 8) acc += s[k] * b2f(V[base + (long)k * BD + d]);
  part[slice][d] = acc;
  __syncthreads();
  if (tid < DH) {
    float ss = 0.f;
    #pragma unroll
    for (int t = 0; t < 8; t++) ss += part[t][tid];
    o[(long)b * BD + h * DH + tid] = ss * inv;
  }
}

// ---------------- relay row ops (fp32 weights; tiny) ----------------
__global__ __launch_bounds__(256) void rowvec_matmul(const float* __restrict__ X, long xstride,
                                                     const float* __restrict__ W,
                                                     float* __restrict__ out) {
  int b = blockIdx.x, tid = threadIdx.x;
  __shared__ float xs[BD];
  xs[tid] = X[(long)b * xstride + tid];
  __syncthreads();
  float acc = 0.f;
  for (int k = 0; k < BD; k++) acc += xs[k] * W[(long)k * BD + tid];
  out[(long)b * BD + tid] = acc;
}

__global__ __launch_bounds__(256) void rowvec_oproj_ln(const float* __restrict__ o,
                                                       const float* __restrict__ Wo,
                                                       const float* __restrict__ Xres, long xstride,
                                                       const float* __restrict__ g,
                                                       const float* __restrict__ beta,
                                                       float* __restrict__ dst, long dstride,
                                                       ushort_t* __restrict__ dsth, long dhstride) {
  int b = blockIdx.x, tid = threadIdx.x;
  __shared__ float xs[BD];
  __shared__ float rs[256], rq[256];
  xs[tid] = o[(long)b * BD + tid];
  __syncthreads();
  float acc = 0.f;
  for (int k = 0; k < BD; k++) acc += xs[k] * Wo[(long)k * BD + tid];
  float v = acc + Xres[(long)b * xstride + tid];
  rs[tid] = v;
  rq[tid] = v * v;
  __syncthreads();
  for (int st = 128; st > 0; st >>= 1) {
    if (tid < st) { rs[tid] += rs[tid + st]; rq[tid] += rq[tid + st]; }
    __syncthreads();
  }
  float mu = rs[0] * (1.f / BD);
  float var = rq[0] * (1.f / BD) - mu * mu;
  float y = (v - mu) * rsqrtf(var + EPSV) * g[tid] + beta[tid];
  dst[(long)b * dstride + tid] = y;
  if (dsth) dsth[(long)b * dhstride + tid] = f2b(y);
}

__global__ __launch_bounds__(256) void ln_residual(const float* __restrict__ OP,
                                                   float* __restrict__ X,
                                                   ushort_t* __restrict__ Xh,
                                                   const float* __restrict__ g,
                                                   const float* __restrict__ beta) {
  long r = blockIdx.x;
  int tid = threadIdx.x;
  __shared__ float rs[256], rq[256];
  float v = OP[r * BD + tid] + X[r * BD + tid];
  rs[tid] = v;
  rq[tid] = v * v;
  __syncthreads();
  for (int st = 128; st > 0; st >>= 1) {
    if (tid < st) { rs[tid] += rs[tid + st]; rq[tid] += rq[tid + st]; }
    __syncthreads();
  }
  float mu = rs[0] * (1.f / BD);
  float var = rq[0] * (1.f / BD) - mu * mu;
  float y = (v - mu) * rsqrtf(var + EPSV) * g[tid] + beta[tid];
  X[r * BD + tid] = y;
  Xh[r * BD + tid] = f2b(y);
}

// ---------------- launch ----------------
extern "C" void kernel_launch(void* const* d_in, const int* in_sizes, int n_in,
                              void* d_out, int out_size, void* d_ws, size_t ws_size,
                              hipStream_t stream) {
  const float* gv    = (const float*)d_in[0];
  const float* graph = (const float*)d_in[1];
  const float* Wq    = (const float*)d_in[2];
  const float* Wk    = (const float*)d_in[3];
  const float* Wv    = (const float*)d_in[4];
  const float* Wo    = (const float*)d_in[5];
  const float* lg    = (const float*)d_in[6];
  const float* lb    = (const float*)d_in[7];
  float* out = (float*)d_out;

  const long S  = (long)NB * LQ * BD;   // 4,198,400
  const long S4 = S * 4, S2 = S * 2;
  char* base = (char*)d_ws;
  // layout: X(S4), Xh(S2), B1(S4), Qh(S2), Kh(S2), Vh(S2), Oh(S2), Wt(2MB), qrel/orel.
  // aliases (time-shared): Ght = B1..Kh (32MB, pre-layer1 only); satT = Vh (pre-layer1);
  // VhT = B1[0..8.9MB] and Mrow = B1[8.9..9.5MB] during self layers (B1 dead until oproj).
  float*    X    = (float*)base;
  ushort_t* Xh   = (ushort_t*)(base + S4);
  float*    B1   = (float*)(base + S4 + S2);
  ushort_t* Qh   = (ushort_t*)(base + 2 * S4 + S2);
  ushort_t* Kh   = (ushort_t*)(base + 2 * S4 + 2 * S2);
  ushort_t* Vh   = (ushort_t*)(base + 2 * S4 + 3 * S2);
  ushort_t* Oh   = (ushort_t*)(base + 2 * S4 + 4 * S2);
  ushort_t* Wt   = (ushort_t*)(base + 2 * S4 + 5 * S2);
  float*    qrel = (float*)(base + 2 * S4 + 5 * S2 + 16L * 65536 * 2);
  float*    orel = qrel + (long)NB * BD;
  ushort_t* Ght  = (ushort_t*)B1;
  ushort_t* satT = Vh;
  ushort_t* VhT  = (ushort_t*)B1;
  float*    Mrow = (float*)((char*)B1 + (long)NB * BD * KP * 2);

  const long WSZ = (long)BD * BD;
  const long XST = (long)LQ * BD;
  dim3 blk(256);

  k_copy_cast<<<dim3(2048), blk, 0, stream>>>(gv, X, Xh, S);
  k_wtrans<<<dim3(64, 16), blk, 0, stream>>>(Wq, Wk, Wv, Wo, Wt);

  // ---- layer 0: relay GAT ----
  rowvec_matmul<<<dim3(NB), blk, 0, stream>>>(X, XST, Wq + 0 * WSZ, qrel);
  gemm_kv<<<dim3(16, 8, NB), blk, 0, stream>>>(Xh, Wt, 0, Kh, Vh);
  attn_relay<<<dim3(NB, NH), blk, 0, stream>>>(qrel, Kh, Vh, orel);
  rowvec_oproj_ln<<<dim3(NB), blk, 0, stream>>>(orel, Wo + 0 * WSZ, X, XST,
                                                lg + 0 * BD, lb + 0 * BD, X, XST, Xh, XST);

  // ---- sat mixing: sat = G^T @ sat (pre-transposed MFMA) ----
  k_gtrans<<<dim3(256, NB), blk, 0, stream>>>(graph, Ght);
  k_satT<<<dim3(64, NB), blk, 0, stream>>>(Xh, satT);
  gemm_gtx2<<<dim3(16, 4, NB), blk, 0, stream>>>(Ght, satT, X, Xh);

  // ---- layers 1,2: self GAT ----
  for (int l = 1; l <= 2; l++) {
    gemm_qkv<<<dim3(257, 12), blk, 0, stream>>>(Xh, Wt, l, Qh, Kh, Vh, NB * LQ);
    k_vtrans<<<dim3(17, 4, NB), blk, 0, stream>>>(Vh, VhT);
    attn_rowmax<<<dim3(9, NH, NB), blk, 0, stream>>>(Qh, Kh, Mrow);
    attn_fa<<<dim3(9, NH, NB), blk, 0, stream>>>(Qh, Kh, VhT, Mrow, Oh);
    gemm_oproj<<<dim3(257, 4), blk, 0, stream>>>(Oh, Wt, l, B1, NB * LQ);
    ln_residual<<<dim3(NB * LQ), blk, 0, stream>>>(B1, X, Xh, lg + l * BD, lb + l * BD);
  }

  // ---- sat_u output ----
  k_sat_out<<<dim3(2048), blk, 0, stream>>>(X, out + (long)NB * BD);

  // ---- layer 3: final relay GAT -> z ----
  rowvec_matmul<<<dim3(NB), blk, 0, stream>>>(X, XST, Wq + 3 * WSZ, qrel);
  gemm_kv<<<dim3(16, 8, NB), blk, 0, stream>>>(Xh, Wt, 3, Kh, Vh);
  attn_relay<<<dim3(NB, NH), blk, 0, stream>>>(qrel, Kh, Vh, orel);
  rowvec_oproj_ln<<<dim3(NB), blk, 0, stream>>>(orel, Wo + 3 * WSZ, X, XST,
                                                lg + 3 * BD, lb + 3 * BD, out, BD, nullptr, 0);
}